// Round 4
// baseline (163.282 us; speedup 1.0000x reference)
//
#include <hip/hip_runtime.h>
#include <math.h>

// Problem constants (B=2, C=128, G=16, Cg=8, K=3, H=W=192)
#define BB 2
#define CC 128
#define GG 16
#define CG 8
#define HH 192
#define WW 192
#define HM 190
#define WM 190
#define HWSZ (HH * WW)        // 36864
#define NTRIPLE (BB * GG * 9) // 288
#define SPLIT 32              // strips per image (31x6 rows + 1x4 rows)
#define RSTRIP 6              // rows per strip

typedef float float4a __attribute__((ext_vector_type(4), aligned(4)));
typedef float float4v __attribute__((ext_vector_type(4)));

// Module-owned scratch (d_ws size unverified; writing it corrupted the
// harness pristine input copy in a previous session). Each array is fully
// rewritten every call before being read; kernel boundaries provide
// agent-scope coherence (no fences anywhere -- R1 lesson: per-block
// __threadfence cost ~70 us in L2 writebacks).
__device__ float g_part[NTRIPLE * SPLIT * 36]; // per-strip partial sums
__device__ int g_rel[BB * GG * 72];            // neighbor rel offset table
__device__ float g_scl[BB * GG * 72];          // c_max/8 table

// Is window row (ci,ki) referenced by any of triple J's 8 vectors?
constexpr bool row_used(int J, int ci, int ki) {
  for (int d = 0; d < 8; ++d) {
    const int f = 8 * J + d;
    if ((f / 9 - (8 * J) / 9) == ci && (f % 9) / 3 == ki) return true;
  }
  return false;
}

// -------- Phase 1: single-wave LDS-staged gram strips ---------------------
// R3 post-mortem: 43us at 13% VALUBusy, unchanged by 2x occupancy -> the
// stall is the shared L1/L2 path (per-CU working set ~80KB >> 32KB L1;
// every windowed float4 load touches 16 lines). v4: each 64-thread block
// stages its strip's channel rows into LDS ONCE (coalesced, <=12 float4
// per lane, 12.3KB) and runs the identical gram arithmetic from LDS.
// Single wave -> no barriers, no cross-wave reduction.
template <int J>
__device__ __forceinline__ void gram_strip(const float* __restrict__ pA,
                                           const float* __restrict__ pB,
                                           float* s_ch, int y0, int rows,
                                           int lane, float acc[36]) {
  constexpr int CA = (8 * J) / 9;
  constexpr int CB = (8 * J + 7) / 9;
  constexpr int NCH = (CB > CA) ? 2 : 1;

  // ---- stage NCH channels x (rows+2) rows x 192 px into LDS ----
  const int rs = rows + 2; // <= 8
  const int nst = NCH * rs * 48; // float4 quads to stage (<= 768)
  for (int t = lane; t < nst; t += 64) {
    const int ch = t / (rs * 48);
    const int rem = t % (rs * 48);
    const int row = rem / 48;
    const int quad = rem % 48;
    const float4v val =
        *(const float4v*)((ch ? pB : pA) + (y0 + row) * WW + quad * 4);
    *(float4v*)(s_ch + (ch * 8 + row) * 192 + quad * 4) = val;
  }
  __syncthreads(); // single wave: ~free, forces the ds_write->ds_read order

  // ---- main: 4-px groups, x0 in {0,4,...,184}, px x in [0,188) ----
  const int ngrp = rows * 47;
  for (int q = lane; q < ngrp; q += 64) {
    const int ly = q / 47;
    const int x0 = (q % 47) * 4; // 16B-aligned LDS address

    float w[NCH][3][8];
#pragma unroll
    for (int ci = 0; ci < NCH; ++ci) {
#pragma unroll
      for (int ki = 0; ki < 3; ++ki) {
        if (row_used(J, ci, ki)) {
          const float* rp = s_ch + (ci * 8 + ly + ki) * 192 + x0;
          const float4v a = *(const float4v*)rp;
          const float4v bq = *(const float4v*)(rp + 4);
          w[ci][ki][0] = a.x; w[ci][ki][1] = a.y;
          w[ci][ki][2] = a.z; w[ci][ki][3] = a.w;
          w[ci][ki][4] = bq.x; w[ci][ki][5] = bq.y;
          w[ci][ki][6] = bq.z; w[ci][ki][7] = bq.w;
        }
      }
    }
    // squares
#pragma unroll
    for (int d = 0; d < 8; ++d) {
      const int f = 8 * J + d;
      const int ci = f / 9 - CA;
      const int k = f % 9;
      const int ki = k / 3, kj = k % 3;
      float s = 0.0f;
#pragma unroll
      for (int e = 0; e < 4; ++e) s += w[ci][ki][kj + e] * w[ci][ki][kj + e];
      acc[d] += s;
    }
    // cross products (same (c,d) order the reduction expects)
    int p = 8;
#pragma unroll
    for (int c = 0; c < 8; ++c) {
      const int f1 = 8 * J + c;
      const int ci1 = f1 / 9 - CA;
      const int k1 = f1 % 9;
      const int ki1 = k1 / 3, kj1 = k1 % 3;
#pragma unroll
      for (int d = c + 1; d < 8; ++d) {
        const int f2 = 8 * J + d;
        const int ci2 = f2 / 9 - CA;
        const int k2 = f2 % 9;
        const int ki2 = k2 / 3, kj2 = k2 % 3;
        float s = 0.0f;
#pragma unroll
        for (int e = 0; e < 4; ++e)
          s += w[ci1][ki1][kj1 + e] * w[ci2][ki2][kj2 + e];
        acc[p++] += s;
      }
    }
  }

  // ---- cleanup: px x in {188,189}, scalar LDS reads ----
  const int ncl = rows * 2;
  for (int t = lane; t < ncl; t += 64) {
    const int ly = t / 2;
    const int x = 188 + (t & 1);
    float v[8];
#pragma unroll
    for (int d = 0; d < 8; ++d) {
      const int f = 8 * J + d;
      const int ci = f / 9 - CA;
      const int k = f % 9;
      const int ki = k / 3, kj = k % 3;
      v[d] = s_ch[(ci * 8 + ly + ki) * 192 + x + kj];
    }
#pragma unroll
    for (int d = 0; d < 8; ++d) acc[d] += v[d] * v[d];
    int p = 8;
#pragma unroll
    for (int c = 0; c < 8; ++c)
#pragma unroll
      for (int d = c + 1; d < 8; ++d) acc[p++] += v[c] * v[d];
  }
}

__global__ __launch_bounds__(64, 4) void phase1_kernel(
    const float* __restrict__ feat) {
  const int B = blockIdx.x;      // 0..9215
  const int xcd = B & 7;         // XCD-locality swizzle
  const int slot = B >> 3;       // 0..1151
  const int unit = xcd * 4 + slot / 288; // (b,g) composite, 0..31
  const int rem = slot % 288;
  const int j = rem / 32;
  const int strip = rem % 32;
  const int b = unit >> 4;
  const int g = unit & 15;

  const int cA = (8 * j) / 9;
  const int cB = (8 * j + 7) / 9;
  const float* pA = feat + (size_t)(b * CC + g * CG + cA) * HWSZ;
  const float* pB = feat + (size_t)(b * CC + g * CG + cB) * HWSZ;

  const int y0 = strip * RSTRIP;
  const int rows = (y0 + RSTRIP <= HM) ? RSTRIP : HM - y0; // 6 or 4 (last)
  const int lane = (int)threadIdx.x;

  __shared__ float s_ch[2 * 8 * 192]; // 12.3 KB -> ~13 blocks/CU by LDS

  float acc[36];
#pragma unroll
  for (int i = 0; i < 36; ++i) acc[i] = 0.0f;

  switch (j) {
    case 0: gram_strip<0>(pA, pB, s_ch, y0, rows, lane, acc); break;
    case 1: gram_strip<1>(pA, pB, s_ch, y0, rows, lane, acc); break;
    case 2: gram_strip<2>(pA, pB, s_ch, y0, rows, lane, acc); break;
    case 3: gram_strip<3>(pA, pB, s_ch, y0, rows, lane, acc); break;
    case 4: gram_strip<4>(pA, pB, s_ch, y0, rows, lane, acc); break;
    case 5: gram_strip<5>(pA, pB, s_ch, y0, rows, lane, acc); break;
    case 6: gram_strip<6>(pA, pB, s_ch, y0, rows, lane, acc); break;
    case 7: gram_strip<7>(pA, pB, s_ch, y0, rows, lane, acc); break;
    default: gram_strip<8>(pA, pB, s_ch, y0, rows, lane, acc); break;
  }

  // 64-lane butterfly; lane 0 stores the 36 strip partials.
  const int tri = unit * 9 + j;
#pragma unroll
  for (int i = 0; i < 36; ++i) {
    float v = acc[i];
    for (int o = 32; o > 0; o >>= 1) v += __shfl_down(v, o, 64);
    if (lane == 0) g_part[(tri * SPLIT + strip) * 36 + i] = v;
  }
}

// -------- Phase 1b: reduce strips, 8x8 argmin, emit phase2 tables ---------
// One block per triple, 36-way-parallel strip reduce (same s-ascending
// order as before -> identical sums), then the serial 8x8 argmin on tid 0.
__global__ __launch_bounds__(64) void phase1b_kernel() {
  const int tri = blockIdx.x;
  const int tid = (int)threadIdx.x;
  const int b = tri / (GG * 9);
  const int rem = tri % (GG * 9);
  const int g = rem / 9;
  const int j = rem % 9;

  __shared__ float s_tot[36];
  if (tid < 36) {
    float t = 0.0f;
    for (int s = 0; s < SPLIT; ++s) // same ascending order as before
      t += g_part[(tri * SPLIT + s) * 36 + tid];
    s_tot[tid] = t;
  }
  __syncthreads();
  if (tid != 0) return;

  float sq[8], gm[8][8];
#pragma unroll
  for (int i = 0; i < 8; ++i) sq[i] = s_tot[i];
  {
    int p = 8;
    for (int c = 0; c < 8; ++c)
      for (int d = c + 1; d < 8; ++d) {
        gm[c][d] = s_tot[p];
        gm[d][c] = s_tot[p];
        ++p;
      }
  }
  // per-row argmin with inf diagonal, first-occurrence tie-break
  int nn[8];
  for (int c = 0; c < 8; ++c) {
    float best = INFINITY;
    int bi = 0;
    for (int d = 0; d < 8; ++d) {
      if (d == c) continue;
      const float d2 = sq[c] + sq[d] - 2.0f * gm[c][d];
      if (d2 < best) {
        best = d2;
        bi = d;
      }
    }
    nn[c] = bi;
  }
  int um = 0;
  for (int c = 0; c < 8; ++c) um = um > nn[c] ? um : nn[c];
  int cnt = 0;
  for (int c = 0; c < 8; ++c) cnt += (nn[c] == um) ? 1 : 0;

  // scale = c_max/8 (exact: int * power of two); rel = neighbor offset
  // relative to the query pixel, constant over (h,w).
  const float sc = (float)cnt * 0.125f;
  const int fn = j * 8 + um;
  const int cn = fn / 9;
  const int kn = fn % 9;
  const int kin = kn / 3, kjn = kn % 3;
  for (int d = 0; d < 8; ++d) {
    const int f = j * 8 + d;
    const int cl = f / 9;
    const int k = f % 9;
    const int ki = k / 3, kj = k % 3;
    const int rel = (cn - cl) * HWSZ + (kin - ki) * WW + (kjn - kj);
    const int tix = (b * GG + g) * 72 + f;
    g_rel[tix] = rel;
    g_scl[tix] = sc;
  }
}

// -------- Phase 2: R0-proven shape (4608 blocks x 2 groups) + fused edge --
// R3 post-mortem: 1024 chunky blocks cost ~8us vs this shape -- revert.
// Table prologue is 18 tiny loads; edge groups (~6%) take the clamped
// scalar else-path (saves the separate edge launch; proven in R2).
__global__ __launch_bounds__(256) void phase2_kernel(
    const float* __restrict__ feat, float* __restrict__ out) {
  const int B = blockIdx.x;      // 0..4607
  const int xcd = B & 7;         // XCD-locality swizzle
  const int slot = B >> 3;       // 0..575
  const int unit = xcd * 4 + slot / 144; // (b,g) composite, 0..31
  const int r = slot % 144;
  const int cl = r / 18;         // local channel 0..7
  const int blk = r % 18;        // 18 x 2048 px = one plane
  const int plane = unit * 8 + cl; // == b*CC + ch
  const int tid = (int)threadIdx.x;

  const int tbase = unit * 72 + cl * 9;
  int rel[9];
  float scl[9];
#pragma unroll
  for (int k = 0; k < 9; ++k) {
    rel[k] = g_rel[tbase + k];
    scl[k] = g_scl[tbase + k];
  }

  const float* pb = feat + (size_t)plane * HWSZ;
  float* ob = out + (size_t)plane * HWSZ;
  const bool b1 = (unit >= GG); // b != 0
  const int i0 = blk * 2048 + tid * 4;

#pragma unroll
  for (int gidx = 0; gidx < 2; ++gidx) {
    const int inner = i0 + gidx * 1024;
    const int h = inner / WW;
    const int w0 = inner % WW; // always a multiple of 4 (WW % 4 == 0)
    if (h >= 2 && h < HM && w0 >= 4 && w0 < 188) {
      // interior: all 9 neighbors valid for all 4 px
      const float* p = pb + inner;
      const float4v v = *(const float4v*)p;
      float4v acc = {0.0f, 0.0f, 0.0f, 0.0f};
#pragma unroll
      for (int k = 0; k < 9; ++k) {
        const float4a n = *(const float4a*)(p + rel[k]);
        const float s = scl[k];
        // exact reference op order: floor(v*n*cm/8) == floor(v*n*(cm/8))
        acc.x += floorf(v.x * n.x * s);
        acc.y += floorf(v.y * n.y * s);
        acc.z += floorf(v.z * n.z * s);
        acc.w += floorf(v.w * n.w * s);
      }
      if (b1) { // interior => n_valid = 9
        acc.x += 9.0f * v.x;
        acc.y += 9.0f * v.y;
        acc.z += 9.0f * v.z;
        acc.w += 9.0f * v.w;
      }
      *(float4v*)(ob + inner) = acc;
    } else {
      // border: clamped scalar path (exec-masked for interior lanes)
#pragma unroll
      for (int e = 0; e < 4; ++e) {
        const int w = w0 + e;
        const float* p = pb + inner + e;
        const float v = *p;
        float acc = 0.0f;
        int nv = 0;
#pragma unroll
        for (int k = 0; k < 9; ++k) {
          const int ki = k / 3, kj = k % 3; // compile-time
          const int y = h - ki, x = w - kj;
          const bool valid =
              ((unsigned)y < (unsigned)HM) & ((unsigned)x < (unsigned)WM);
          const int o = valid ? rel[k] : 0; // clamp keeps the load in-bounds
          const float n = p[o];
          const float fl = floorf(v * n * scl[k]);
          acc += valid ? fl : 0.0f;
          nv += valid ? 1 : 0;
        }
        if (b1) acc += (float)nv * v;
        ob[inner + e] = acc;
      }
    }
  }
}

extern "C" void kernel_launch(void* const* d_in, const int* in_sizes, int n_in,
                              void* d_out, int out_size, void* d_ws,
                              size_t ws_size, hipStream_t stream) {
  const float* feat = (const float*)d_in[0];
  float* out = (float*)d_out;
  (void)d_ws;
  (void)ws_size;
  (void)in_sizes;
  (void)n_in;
  (void)out_size;

  phase1_kernel<<<NTRIPLE * SPLIT, 64, 0, stream>>>(feat);
  phase1b_kernel<<<NTRIPLE, 64, 0, stream>>>();
  phase2_kernel<<<BB * CC * 18, 256, 0, stream>>>(feat, out);
}

// Round 5
// 143.750 us; speedup vs baseline: 1.1359x; 1.1359x over previous
//
#include <hip/hip_runtime.h>
#include <math.h>

// Problem constants (B=2, C=128, G=16, Cg=8, K=3, H=W=192)
#define BB 2
#define CC 128
#define GG 16
#define CG 8
#define HH 192
#define WW 192
#define HM 190
#define WM 190
#define HWSZ (HH * WW)        // 36864
#define NTRIPLE (BB * GG * 9) // 288
#define SPLIT 8               // regions per image (7x24 rows + 1x22)
#define RREG 24               // output rows per region

typedef float float4a __attribute__((ext_vector_type(4), aligned(4)));
typedef float float4v __attribute__((ext_vector_type(4)));

// Module-owned scratch (d_ws size unverified; writing it corrupted the
// harness pristine input copy in a previous session). Each array is fully
// rewritten every call before being read; kernel boundaries provide
// agent-scope coherence (no fences anywhere -- R1 lesson: per-block
// __threadfence cost ~70 us in L2 writebacks).
__device__ float g_part[NTRIPLE * SPLIT * 36]; // per-region partial sums
__device__ int g_rel[BB * GG * 72];            // neighbor rel offset table
__device__ float g_scl[BB * GG * 72];          // c_max/8 table

// Is window row (ci,ki) referenced by any of triple J's 8 vectors?
constexpr bool row_used(int J, int ci, int ki) {
  for (int d = 0; d < 8; ++d) {
    const int f = 8 * J + d;
    if ((f / 9 - (8 * J) / 9) == ci && (f % 9) / 3 == ki) return true;
  }
  return false;
}

// -------- Phase 1: multi-wave LDS-staged gram regions ---------------------
// R4 post-mortem: single-wave LDS blocks serialized stage->compute at 26%
// occupancy (63us). R3: 2x waves on the direct-global version didn't help
// (43us) -> that version is L1-thrash/L2-re-read bound (3-row windows
// refetch each line ~3x). v5 = conjunction: LDS staging (compulsory-only
// global traffic) + 4-wave blocks at 4 blocks/CU (LDS-bound, 16 waves/CU)
// so staging of one block hides under compute of the other three.
template <int J>
__device__ __forceinline__ void gram_region(float* s_ch, int rows, int tid,
                                            float acc[36]) {
  constexpr int CA = (8 * J) / 9;
  constexpr int CB = (8 * J + 7) / 9;
  constexpr int NCH = (CB > CA) ? 2 : 1;

  // ---- main: 4-px groups, x0 in {0,4,...,184}, px x in [0,188) ----
  const int ngrp = rows * 47;
  for (int q = tid; q < ngrp; q += 256) {
    const int ly = q / 47;
    const int x0 = (q % 47) * 4; // 16B-aligned LDS address

    float w[NCH][3][8];
#pragma unroll
    for (int ci = 0; ci < NCH; ++ci) {
#pragma unroll
      for (int ki = 0; ki < 3; ++ki) {
        if (row_used(J, ci, ki)) {
          const float* rp = s_ch + (ci * 26 + ly + ki) * 192 + x0;
          const float4v a = *(const float4v*)rp;
          const float4v bq = *(const float4v*)(rp + 4);
          w[ci][ki][0] = a.x; w[ci][ki][1] = a.y;
          w[ci][ki][2] = a.z; w[ci][ki][3] = a.w;
          w[ci][ki][4] = bq.x; w[ci][ki][5] = bq.y;
          w[ci][ki][6] = bq.z; w[ci][ki][7] = bq.w;
        }
      }
    }
    // squares
#pragma unroll
    for (int d = 0; d < 8; ++d) {
      const int f = 8 * J + d;
      const int ci = f / 9 - CA;
      const int k = f % 9;
      const int ki = k / 3, kj = k % 3;
      float s = 0.0f;
#pragma unroll
      for (int e = 0; e < 4; ++e) s += w[ci][ki][kj + e] * w[ci][ki][kj + e];
      acc[d] += s;
    }
    // cross products (same (c,d) order the reduction expects)
    int p = 8;
#pragma unroll
    for (int c = 0; c < 8; ++c) {
      const int f1 = 8 * J + c;
      const int ci1 = f1 / 9 - CA;
      const int k1 = f1 % 9;
      const int ki1 = k1 / 3, kj1 = k1 % 3;
#pragma unroll
      for (int d = c + 1; d < 8; ++d) {
        const int f2 = 8 * J + d;
        const int ci2 = f2 / 9 - CA;
        const int k2 = f2 % 9;
        const int ki2 = k2 / 3, kj2 = k2 % 3;
        float s = 0.0f;
#pragma unroll
        for (int e = 0; e < 4; ++e)
          s += w[ci1][ki1][kj1 + e] * w[ci2][ki2][kj2 + e];
        acc[p++] += s;
      }
    }
  }

  // ---- cleanup: px x in {188,189}, scalar LDS reads ----
  const int ncl = rows * 2;
  for (int t = tid; t < ncl; t += 256) {
    const int ly = t / 2;
    const int x = 188 + (t & 1);
    float v[8];
#pragma unroll
    for (int d = 0; d < 8; ++d) {
      const int f = 8 * J + d;
      const int ci = f / 9 - CA;
      const int k = f % 9;
      const int ki = k / 3, kj = k % 3;
      v[d] = s_ch[(ci * 26 + ly + ki) * 192 + x + kj];
    }
#pragma unroll
    for (int d = 0; d < 8; ++d) acc[d] += v[d] * v[d];
    int p = 8;
#pragma unroll
    for (int c = 0; c < 8; ++c)
#pragma unroll
      for (int d = c + 1; d < 8; ++d) acc[p++] += v[c] * v[d];
  }
}

__global__ __launch_bounds__(256, 2) void phase1_kernel(
    const float* __restrict__ feat) {
  const int B = blockIdx.x;      // 0..2303
  const int xcd = B & 7;         // XCD-locality swizzle
  const int slot = B >> 3;       // 0..287
  const int unit = xcd * 4 + slot / 72; // (b,g) composite, 0..31
  const int rem = slot % 72;
  const int j = rem / 8;
  const int region = rem % 8;
  const int b = unit >> 4;
  const int g = unit & 15;

  const int cA = (8 * j) / 9;
  const int cB = (8 * j + 7) / 9;
  const int nch = (cB > cA) ? 2 : 1;
  const float* pA = feat + (size_t)(b * CC + g * CG + cA) * HWSZ;
  const float* pB = feat + (size_t)(b * CC + g * CG + cB) * HWSZ;

  const int y0 = region * RREG;
  const int rows = (y0 + RREG <= HM) ? RREG : HM - y0; // 24, last region 22
  const int tid = (int)threadIdx.x;

  // 2ch x 26 rows x 192 px = 39KB -> 4 blocks/CU (16 waves/CU)
  __shared__ float s_ch[2 * 26 * 192];

  // ---- cooperative stage: nch*(rows+2) rows, coalesced float4 ----
  const int rs = rows + 2; // <= 26; y0+rs <= 192 always
  const int nst = nch * rs * 48;
  for (int t = tid; t < nst; t += 256) {
    const int ch = t / (rs * 48);
    const int r2 = t % (rs * 48);
    const int row = r2 / 48;
    const int quad = r2 % 48;
    const float4v val =
        *(const float4v*)((ch ? pB : pA) + (y0 + row) * WW + quad * 4);
    *(float4v*)(s_ch + (ch * 26 + row) * 192 + quad * 4) = val;
  }
  __syncthreads();

  float acc[36];
#pragma unroll
  for (int i = 0; i < 36; ++i) acc[i] = 0.0f;

  switch (j) {
    case 0: gram_region<0>(s_ch, rows, tid, acc); break;
    case 1: gram_region<1>(s_ch, rows, tid, acc); break;
    case 2: gram_region<2>(s_ch, rows, tid, acc); break;
    case 3: gram_region<3>(s_ch, rows, tid, acc); break;
    case 4: gram_region<4>(s_ch, rows, tid, acc); break;
    case 5: gram_region<5>(s_ch, rows, tid, acc); break;
    case 6: gram_region<6>(s_ch, rows, tid, acc); break;
    case 7: gram_region<7>(s_ch, rows, tid, acc); break;
    default: gram_region<8>(s_ch, rows, tid, acc); break;
  }

  // Wave butterfly then cross-wave via s_ch (reused -> no extra LDS).
  __syncthreads(); // all LDS reads of the tile are done
  float* red = s_ch;
  const int lane = tid & 63;
  const int wave = tid >> 6;
#pragma unroll
  for (int i = 0; i < 36; ++i) {
    float v = acc[i];
    for (int o = 32; o > 0; o >>= 1) v += __shfl_down(v, o, 64);
    if (lane == 0) red[i * 4 + wave] = v;
  }
  __syncthreads();
  if (tid < 36) {
    const int tri = unit * 9 + j;
    g_part[(tri * SPLIT + region) * 36 + tid] =
        ((red[tid * 4] + red[tid * 4 + 1]) + red[tid * 4 + 2]) +
        red[tid * 4 + 3];
  }
}

// -------- Phase 1b: reduce regions, 8x8 argmin, emit phase2 tables --------
// One block per triple; 36-way-parallel region reduce (ascending s order,
// as in all passing rounds), serial 8x8 argmin on tid 0.
__global__ __launch_bounds__(64) void phase1b_kernel() {
  const int tri = blockIdx.x;
  const int tid = (int)threadIdx.x;
  const int b = tri / (GG * 9);
  const int rem = tri % (GG * 9);
  const int g = rem / 9;
  const int j = rem % 9;

  __shared__ float s_tot[36];
  if (tid < 36) {
    float t = 0.0f;
    for (int s = 0; s < SPLIT; ++s)
      t += g_part[(tri * SPLIT + s) * 36 + tid];
    s_tot[tid] = t;
  }
  __syncthreads();
  if (tid != 0) return;

  float sq[8], gm[8][8];
#pragma unroll
  for (int i = 0; i < 8; ++i) sq[i] = s_tot[i];
  {
    int p = 8;
    for (int c = 0; c < 8; ++c)
      for (int d = c + 1; d < 8; ++d) {
        gm[c][d] = s_tot[p];
        gm[d][c] = s_tot[p];
        ++p;
      }
  }
  // per-row argmin with inf diagonal, first-occurrence tie-break
  int nn[8];
  for (int c = 0; c < 8; ++c) {
    float best = INFINITY;
    int bi = 0;
    for (int d = 0; d < 8; ++d) {
      if (d == c) continue;
      const float d2 = sq[c] + sq[d] - 2.0f * gm[c][d];
      if (d2 < best) {
        best = d2;
        bi = d;
      }
    }
    nn[c] = bi;
  }
  int um = 0;
  for (int c = 0; c < 8; ++c) um = um > nn[c] ? um : nn[c];
  int cnt = 0;
  for (int c = 0; c < 8; ++c) cnt += (nn[c] == um) ? 1 : 0;

  // scale = c_max/8 (exact: int * power of two); rel = neighbor offset
  // relative to the query pixel, constant over (h,w).
  const float sc = (float)cnt * 0.125f;
  const int fn = j * 8 + um;
  const int cn = fn / 9;
  const int kn = fn % 9;
  const int kin = kn / 3, kjn = kn % 3;
  for (int d = 0; d < 8; ++d) {
    const int f = j * 8 + d;
    const int cl = f / 9;
    const int k = f % 9;
    const int ki = k / 3, kj = k % 3;
    const int rel = (cn - cl) * HWSZ + (kin - ki) * WW + (kjn - kj);
    const int tix = (b * GG + g) * 72 + f;
    g_rel[tix] = rel;
    g_scl[tix] = sc;
  }
}

// -------- Phase 2 main: interior float4 groups, no edge branch ------------
// R4 post-mortem: fusing the edge path into this kernel cost ~8us (code
// bloat / VGPR pressure in the hot kernel). Revert to the R0-proven split:
// this kernel skips edge groups entirely; phase2_edge writes them.
__global__ __launch_bounds__(256) void phase2_main_kernel(
    const float* __restrict__ feat, float* __restrict__ out) {
  const int B = blockIdx.x;      // 0..4607
  const int xcd = B & 7;         // XCD-locality swizzle
  const int slot = B >> 3;       // 0..575
  const int unit = xcd * 4 + slot / 144; // (b,g) composite, 0..31
  const int r = slot % 144;
  const int cl = r / 18;         // local channel 0..7
  const int blk = r % 18;        // 18 x 2048 px = one plane
  const int plane = unit * 8 + cl; // == b*CC + ch

  const int tbase = unit * 72 + cl * 9;
  int rel[9];
  float scl[9];
#pragma unroll
  for (int k = 0; k < 9; ++k) {
    rel[k] = g_rel[tbase + k];
    scl[k] = g_scl[tbase + k];
  }

  const float* pb = feat + (size_t)plane * HWSZ;
  float* ob = out + (size_t)plane * HWSZ;
  const bool b1 = (unit >= GG); // b != 0
  const int i0 = blk * 2048 + (int)threadIdx.x * 4;

#pragma unroll
  for (int gidx = 0; gidx < 2; ++gidx) {
    const int inner = i0 + gidx * 1024;
    const int h = inner / WW;
    const int w0 = inner % WW;
    if (h >= 2 && h < HM && w0 >= 4 && w0 < 188) {
      const float* p = pb + inner;
      const float4v v = *(const float4v*)p;
      float4v acc = {0.0f, 0.0f, 0.0f, 0.0f};
#pragma unroll
      for (int k = 0; k < 9; ++k) {
        const float4a n = *(const float4a*)(p + rel[k]);
        const float s = scl[k];
        // exact reference op order: floor(v*n*cm/8) == floor(v*n*(cm/8))
        acc.x += floorf(v.x * n.x * s);
        acc.y += floorf(v.y * n.y * s);
        acc.z += floorf(v.z * n.z * s);
        acc.w += floorf(v.w * n.w * s);
      }
      if (b1) { // interior => n_valid = 9
        acc.x += 9.0f * v.x;
        acc.y += 9.0f * v.y;
        acc.z += 9.0f * v.z;
        acc.w += 9.0f * v.w;
      }
      *(float4v*)(ob + inner) = acc;
    }
  }
}

// -------- Phase 2 edge: border pixels, clamped scalar path ----------------
// 2272 px per plane: rows {0,1,190,191} (768) + cols {0..3,188..191} for
// h in [2,190) (1504). 256 planes * 2272 = 581632 = 2272 blocks * 256.
__global__ __launch_bounds__(256) void phase2_edge_kernel(
    const float* __restrict__ feat, float* __restrict__ out) {
  const int gid = blockIdx.x * 256 + (int)threadIdx.x;
  const int plane = gid / 2272;
  const int ei = gid % 2272;
  int h, w;
  if (ei < 768) {
    const int r = ei / WW; // 0..3
    h = (r < 2) ? r : r + 188; // 0,1,190,191
    w = ei % WW;
  } else {
    const int e2 = ei - 768;
    h = 2 + (e2 >> 3);
    const int w8 = e2 & 7;
    w = (w8 < 4) ? w8 : w8 + 184; // 0..3, 188..191
  }
  const int g = (plane % CC) >> 3;
  const int cl = (plane % CC) & 7;
  const int tbase = ((plane / CC) * GG + g) * 72 + cl * 9;

  int rel[9];
  float scl[9];
#pragma unroll
  for (int k = 0; k < 9; ++k) {
    rel[k] = g_rel[tbase + k];
    scl[k] = g_scl[tbase + k];
  }

  const int idx = plane * HWSZ + h * WW + w;
  const float* p = feat + idx;
  const float v = *p;
  float acc = 0.0f;
  int nv = 0;
#pragma unroll
  for (int k = 0; k < 9; ++k) {
    const int ki = k / 3, kj = k % 3; // compile-time
    const int y = h - ki, x = w - kj;
    const bool valid = ((unsigned)y < (unsigned)HM) & ((unsigned)x < (unsigned)WM);
    const int o = valid ? rel[k] : 0; // clamp keeps the load in-bounds
    const float n = p[o];
    const float fl = floorf(v * n * scl[k]);
    acc += valid ? fl : 0.0f;
    nv += valid ? 1 : 0;
  }
  if (plane >= CC) acc += (float)nv * v;
  out[idx] = acc;
}

extern "C" void kernel_launch(void* const* d_in, const int* in_sizes, int n_in,
                              void* d_out, int out_size, void* d_ws,
                              size_t ws_size, hipStream_t stream) {
  const float* feat = (const float*)d_in[0];
  float* out = (float*)d_out;
  (void)d_ws;
  (void)ws_size;
  (void)in_sizes;
  (void)n_in;
  (void)out_size;

  phase1_kernel<<<NTRIPLE * SPLIT, 256, 0, stream>>>(feat);
  phase1b_kernel<<<NTRIPLE, 64, 0, stream>>>();
  phase2_main_kernel<<<BB * CC * 18, 256, 0, stream>>>(feat, out);
  phase2_edge_kernel<<<2272, 256, 0, stream>>>(feat, out);
}